// Round 9
// baseline (189.574 us; speedup 1.0000x reference)
//
#include <hip/hip_runtime.h>

// LSTM: T=512, B=4096, IN=1, H=12.
// R9 = R8 with the chunk-boundary bug fixed.
// R8's x-projection hoist used a stale xq at the last step of each chunk
// (group prefetch stops at the chunk edge) and only re-folded x at tc==0 ->
// steps 64,128,...,448 got x_{t-4}; recurrence propagated it (absmax 0.119).
// Fix: (1) last step of a chunk hoists only the biases (gif0=bif,ggo0=bgo);
// (2) EVERY chunk start folds x_{tc} into gif0/ggo0 after the group-0 xq
// read (2 pkfma on-chain once per 64 steps - negligible).
// Rest unchanged from R8:
//  - xchunk rows padded to 68 floats (kills R7's 4-way bank conflict).
//  - xq prefetched one 4-step group ahead (ds_read_b128 latency buried).
//  - x-projection hoisted off the post-gate chain into the tail shadow.
//  - one cell per 16-lane DPP row (lanes 12..15 clones), 4 cells/wave,
//    1024 single-wave blocks (all SIMDs busy), h exchanged with 15
//    v_mov_b32 dpp row_ror (probed direction, zero-gated per-source
//    weights), fc via ring ror-reduce, pre-scaled weights
//    (sigmoid -log2e, tanh +2log2e), launch_bounds(64,1).

#define TT    512
#define NB    4096
#define HH    12
#define RPW   4      // rows (cells) per wave
#define CHUNK 64     // X staging chunk; TT % CHUNK == 0
#define XPAD  68     // padded row stride (floats): +4 breaks bank aliasing

typedef float v2f __attribute__((ext_vector_type(2)));

static __device__ __forceinline__ v2f pkfma(v2f a, v2f b, v2f c) {
#if __has_builtin(__builtin_elementwise_fma)
    return __builtin_elementwise_fma(a, b, c);
#else
    v2f r; r.x = fmaf(a.x, b.x, c.x); r.y = fmaf(a.y, b.y, c.y); return r;
#endif
}

#define SNEG (-1.44269504088896340736f)   // sigmoid pre-scale: -log2(e)
#define SPOS ( 2.88539008177792681472f)   // tanh pre-scale: +2*log2(e)

#define ROR(r) (0x120 + (r))              // DPP ctrl: row_ror:r

__global__ __launch_bounds__(64, 1)
void lstm_fused(const float* __restrict__ X,
                const float* __restrict__ W_ih,
                const float* __restrict__ W_hh,
                const float* __restrict__ b_ih,
                const float* __restrict__ b_hh,
                const float* __restrict__ fc_w,
                const float* __restrict__ fc_b,
                float* __restrict__ out)
{
    __shared__ float xchunk[RPW][XPAD];   // transposed + padded: [row][time]

    const int lane = threadIdx.x;        // 0..63
    const int row  = lane >> 4;          // 0..3  : cell slot
    const int j    = lane & 15;          // 0..11 real, 12..15 clone lanes
    const int cellbase = blockIdx.x * RPW;
    const int cell = cellbase + row;     // grid sized so cell < NB always

    // ---- probe DPP ror direction: sid[r] = within-row source lane of ror r
    int sid[16];
    sid[0] = j;
#define PROBE(r) sid[r] = __builtin_amdgcn_update_dpp(0, j, ROR(r), 0xF, 0xF, true);
    PROBE(1)  PROBE(2)  PROBE(3)  PROBE(4)  PROBE(5)
    PROBE(6)  PROBE(7)  PROBE(8)  PROBE(9)  PROBE(10)
    PROBE(11) PROBE(12) PROBE(13) PROBE(14) PROBE(15)
#undef PROBE

    // ---- per-source-slot gate weight tables (r=0 is local contribution)
    const int jc = (j < HH) ? j : (HH - 1);   // clamp clone lanes (finite)
    v2f wifU[16], wgoU[16];
    #pragma unroll
    for (int r = 0; r < 16; ++r) {
        const int  s  = sid[r];
        const int  sc = (s < HH) ? s : (HH - 1);
        const float g = ((j >= HH) || (s < HH)) ? 1.0f : 0.0f;
        wifU[r].x = g * SNEG * W_hh[(0 * HH + jc) * HH + sc];
        wifU[r].y = g * SNEG * W_hh[(1 * HH + jc) * HH + sc];
        wgoU[r].x = g * SPOS * W_hh[(2 * HH + jc) * HH + sc];
        wgoU[r].y = g * SNEG * W_hh[(3 * HH + jc) * HH + sc];
    }
    v2f bif, bgo, wxif, wxgo;
    bif.x  = SNEG * (b_ih[0 * HH + jc] + b_hh[0 * HH + jc]);
    bif.y  = SNEG * (b_ih[1 * HH + jc] + b_hh[1 * HH + jc]);
    bgo.x  = SPOS * (b_ih[2 * HH + jc] + b_hh[2 * HH + jc]);
    bgo.y  = SNEG * (b_ih[3 * HH + jc] + b_hh[3 * HH + jc]);
    wxif.x = SNEG * W_ih[0 * HH + jc];   // IN == 1, W_ih flat [48]
    wxif.y = SNEG * W_ih[1 * HH + jc];
    wxgo.x = SPOS * W_ih[2 * HH + jc];
    wxgo.y = SNEG * W_ih[3 * HH + jc];
    const float fcb  = fc_b[0];
    const float fcwj = (j < HH) ? fc_w[j] : 0.0f;   // clones contribute 0

    float cst = 0.0f;    // my cell-state element c[cell][j]
    float hn  = 0.0f;    // my h element h[cell][j]  (h0 = 0)
    int hbits = 0;

    // prefetch chunk 0 of X into registers
    float4 gq = *(const float4*)(X + (size_t)lane * NB + cellbase);

    // running "starting accumulators" for the NEXT step. Invariant: at the
    // first step of each chunk they hold ONLY the biases; x_{tc} is folded
    // right after the chunk's group-0 xq read below.
    v2f gif0 = bif, ggo0 = bgo;

    for (int tc = 0; tc < TT; tc += CHUNK) {
        // stage prefetched chunk to LDS (transposed/padded), prefetch next
        xchunk[0][lane] = gq.x;
        xchunk[1][lane] = gq.y;
        xchunk[2][lane] = gq.z;
        xchunk[3][lane] = gq.w;
        if (tc + CHUNK < TT)
            gq = *(const float4*)(X + (size_t)(tc + CHUNK + lane) * NB + cellbase);

        // prime the xq pipeline: group 0 of this chunk, and fold x_{tc}
        // into the step-(tc) accumulators (they hold only biases here).
        float4 xq = *(const float4*)&xchunk[row][0];
        {
            v2f xvv; xvv.x = xq.x; xvv.y = xq.x;
            gif0 = pkfma(xvv, wxif, gif0);
            ggo0 = pkfma(xvv, wxgo, ggo0);
        }

        for (int t4 = 0; t4 < CHUNK; t4 += 4) {
            const float xs[4] = {xq.x, xq.y, xq.z, xq.w};
            const bool last_group = (t4 + 4 >= CHUNK);
            // prefetch next group's x one group ahead (consumed ~240 cyc later)
            if (!last_group)
                xq = *(const float4*)&xchunk[row][t4 + 4];

            #pragma unroll
            for (int u = 0; u < 4; ++u) {
                // gather h_{t-1} + gate accumulation: local + 15 DPP rors.
                // Accumulators already contain bias + x_t (hoisted).
                v2f gifA = gif0, goA = ggo0;
                v2f gifB; gifB.x = 0.0f; gifB.y = 0.0f;
                v2f goB;  goB.x  = 0.0f; goB.y  = 0.0f;
                {   // local contribution (r = 0)
                    v2f hk; hk.x = hn; hk.y = hn;
                    gifA = pkfma(wifU[0], hk, gifA);
                    goA  = pkfma(wgoU[0], hk, goA);
                }
#define XR(r) { \
                const int hr_##r = __builtin_amdgcn_update_dpp(0, hbits, ROR(r), 0xF, 0xF, true); \
                const float hf = __int_as_float(hr_##r); \
                v2f hk; hk.x = hf; hk.y = hf; \
                if ((r) < 8) { gifA = pkfma(wifU[r], hk, gifA); goA = pkfma(wgoU[r], hk, goA); } \
                else         { gifB = pkfma(wifU[r], hk, gifB); goB = pkfma(wgoU[r], hk, goB); } }
                XR(1)  XR(2)  XR(3)  XR(4)  XR(5)
                XR(6)  XR(7)  XR(8)  XR(9)  XR(10)
                XR(11) XR(12) XR(13) XR(14) XR(15)
#undef XR
                const v2f gif = gifA + gifB;     // v_pk_add_f32 -> feeds exp2
                const v2f ggo = goA + goB;

                // activations (pre-scaled: rcp(1+exp2(g)) directly)
                const float si = __builtin_amdgcn_rcpf(1.0f + __builtin_amdgcn_exp2f(gif.x));
                const float sf = __builtin_amdgcn_rcpf(1.0f + __builtin_amdgcn_exp2f(gif.y));
                const float rg = __builtin_amdgcn_rcpf(1.0f + __builtin_amdgcn_exp2f(ggo.x));
                const float so = __builtin_amdgcn_rcpf(1.0f + __builtin_amdgcn_exp2f(ggo.y));
                const float tg = fmaf(-2.0f, rg, 1.0f);
                cst = fmaf(sf, cst, si * tg);
                const float rc   = __builtin_amdgcn_rcpf(1.0f + __builtin_amdgcn_exp2f(SPOS * cst));
                const float m2so = -2.0f * so;
                hn    = fmaf(m2so, rc, so);
                hbits = __float_as_int(hn);

                // --- tail shadow work (independent of the chain above): ---
                // (a) next step's starting accumulators. Within a group:
                // xs[u+1]; last step of a group: freshly-prefetched xq.x;
                // last step of the CHUNK: biases only (x folded at next
                // chunk's start — next chunk's x is not readable here).
                if (u < 3) {
                    v2f xvv; xvv.x = xs[u + 1]; xvv.y = xs[u + 1];
                    gif0 = pkfma(xvv, wxif, bif);
                    ggo0 = pkfma(xvv, wxgo, bgo);
                } else if (!last_group) {
                    v2f xvv; xvv.x = xq.x; xvv.y = xq.x;
                    gif0 = pkfma(xvv, wxif, bif);
                    ggo0 = pkfma(xvv, wxgo, bgo);
                } else {
                    gif0 = bif;
                    ggo0 = bgo;
                }
                // (b) fc output for step t: ring all-reduce of hn*fcw
                float p = hn * fcwj;
                p += __int_as_float(__builtin_amdgcn_update_dpp(0, __float_as_int(p), ROR(8), 0xF, 0xF, true));
                p += __int_as_float(__builtin_amdgcn_update_dpp(0, __float_as_int(p), ROR(4), 0xF, 0xF, true));
                p += __int_as_float(__builtin_amdgcn_update_dpp(0, __float_as_int(p), ROR(2), 0xF, 0xF, true));
                p += __int_as_float(__builtin_amdgcn_update_dpp(0, __float_as_int(p), ROR(1), 0xF, 0xF, true));
                if (j == 0) out[(size_t)(tc + t4 + u) * NB + cell] = p + fcb;
            }
        }
    }
}

extern "C" void kernel_launch(void* const* d_in, const int* in_sizes, int n_in,
                              void* d_out, int out_size, void* d_ws, size_t ws_size,
                              hipStream_t stream) {
    const float* X    = (const float*)d_in[0];
    const float* W_ih = (const float*)d_in[1];
    const float* W_hh = (const float*)d_in[2];
    const float* b_ih = (const float*)d_in[3];
    const float* b_hh = (const float*)d_in[4];
    const float* fc_w = (const float*)d_in[5];
    const float* fc_b = (const float*)d_in[6];
    float* out = (float*)d_out;

    const int grid = NB / RPW;   // 1024 single-wave blocks: every SIMD busy
    lstm_fused<<<grid, 64, 0, stream>>>(X, W_ih, W_hh, b_ih, b_hh, fc_w, fc_b, out);
}

// Round 10
// 182.840 us; speedup vs baseline: 1.0368x; 1.0368x over previous
//
#include <hip/hip_runtime.h>

// LSTM: T=512, B=4096, IN=1, H=12.
// R10 = R7 (best measured: 133.8 us) + R8's one pure win: xchunk row pad
// to 68 floats (kills R7's 524288 4-way bank-conflict cycles). The R8/R9
// x-projection hoist is REVERTED: its branchy tail-shadow select chains
// cost more issue than the ~8 chain cycles it saved (R9: 137.0 us > R7).
//
// Structure (stable since R6/R7):
//  - one cell per 16-lane DPP row (j = lane&15; lanes 12..15 finite clones),
//    4 cells/wave, 1024 single-wave blocks = every SIMD busy.
//  - h exchanged with 15 v_mov_b32 dpp row_ror (direction probed at setup;
//    per-source-slot weight tables, zero-gated for clone sources).
//  - gates: 2-way-split pk_fma chains, weights pre-scaled
//    (sigmoid: -log2e, tanh-g: +2log2e) so activations are rcp(1+exp2(g)).
//  - fc dot: ring ror-reduce (mul + 4x ror-add) in the step tail.
//  - X: chunk of 64 steps staged to LDS transposed [row][time] (padded),
//    global prefetch one chunk ahead; xq read b128 once per 4 steps,
//    consumed last (x-proj after the ror block).
//  - launch_bounds(64,1): no spills (R4 lesson).
// Plateau evidence: R7 133.8 / R9 137.0 us; period ~430 effective cyc/step
// = irreducible serial chain (gate tree + 2 transcendental chains) + issue
// at 1 wave/SIMD. This is the floor for this decomposition.

#define TT    512
#define NB    4096
#define HH    12
#define RPW   4      // rows (cells) per wave
#define CHUNK 64     // X staging chunk; TT % CHUNK == 0
#define XPAD  68     // padded row stride (floats): +4 breaks bank aliasing

typedef float v2f __attribute__((ext_vector_type(2)));

static __device__ __forceinline__ v2f pkfma(v2f a, v2f b, v2f c) {
#if __has_builtin(__builtin_elementwise_fma)
    return __builtin_elementwise_fma(a, b, c);
#else
    v2f r; r.x = fmaf(a.x, b.x, c.x); r.y = fmaf(a.y, b.y, c.y); return r;
#endif
}

#define SNEG (-1.44269504088896340736f)   // sigmoid pre-scale: -log2(e)
#define SPOS ( 2.88539008177792681472f)   // tanh pre-scale: +2*log2(e)

#define ROR(r) (0x120 + (r))              // DPP ctrl: row_ror:r

__global__ __launch_bounds__(64, 1)
void lstm_fused(const float* __restrict__ X,
                const float* __restrict__ W_ih,
                const float* __restrict__ W_hh,
                const float* __restrict__ b_ih,
                const float* __restrict__ b_hh,
                const float* __restrict__ fc_w,
                const float* __restrict__ fc_b,
                float* __restrict__ out)
{
    __shared__ float xchunk[RPW][XPAD];   // transposed + padded: [row][time]

    const int lane = threadIdx.x;        // 0..63
    const int row  = lane >> 4;          // 0..3  : cell slot
    const int j    = lane & 15;          // 0..11 real, 12..15 clone lanes
    const int cellbase = blockIdx.x * RPW;
    const int cell = cellbase + row;     // grid sized so cell < NB always

    // ---- probe DPP ror direction: sid[r] = within-row source lane of ror r
    int sid[16];
    sid[0] = j;
#define PROBE(r) sid[r] = __builtin_amdgcn_update_dpp(0, j, ROR(r), 0xF, 0xF, true);
    PROBE(1)  PROBE(2)  PROBE(3)  PROBE(4)  PROBE(5)
    PROBE(6)  PROBE(7)  PROBE(8)  PROBE(9)  PROBE(10)
    PROBE(11) PROBE(12) PROBE(13) PROBE(14) PROBE(15)
#undef PROBE

    // ---- per-source-slot gate weight tables (r=0 is local contribution)
    const int jc = (j < HH) ? j : (HH - 1);   // clamp clone lanes (finite)
    v2f wifU[16], wgoU[16];
    #pragma unroll
    for (int r = 0; r < 16; ++r) {
        const int  s  = sid[r];
        const int  sc = (s < HH) ? s : (HH - 1);
        const float g = ((j >= HH) || (s < HH)) ? 1.0f : 0.0f;
        wifU[r].x = g * SNEG * W_hh[(0 * HH + jc) * HH + sc];
        wifU[r].y = g * SNEG * W_hh[(1 * HH + jc) * HH + sc];
        wgoU[r].x = g * SPOS * W_hh[(2 * HH + jc) * HH + sc];
        wgoU[r].y = g * SNEG * W_hh[(3 * HH + jc) * HH + sc];
    }
    v2f bif, bgo, wxif, wxgo;
    bif.x  = SNEG * (b_ih[0 * HH + jc] + b_hh[0 * HH + jc]);
    bif.y  = SNEG * (b_ih[1 * HH + jc] + b_hh[1 * HH + jc]);
    bgo.x  = SPOS * (b_ih[2 * HH + jc] + b_hh[2 * HH + jc]);
    bgo.y  = SNEG * (b_ih[3 * HH + jc] + b_hh[3 * HH + jc]);
    wxif.x = SNEG * W_ih[0 * HH + jc];   // IN == 1, W_ih flat [48]
    wxif.y = SNEG * W_ih[1 * HH + jc];
    wxgo.x = SPOS * W_ih[2 * HH + jc];
    wxgo.y = SNEG * W_ih[3 * HH + jc];
    const float fcb  = fc_b[0];
    const float fcwj = (j < HH) ? fc_w[j] : 0.0f;   // clones contribute 0

    float cst = 0.0f;    // my cell-state element c[cell][j]
    float hn  = 0.0f;    // my h element h[cell][j]  (h0 = 0)
    int hbits = 0;

    // prefetch chunk 0 of X into registers
    float4 gq = *(const float4*)(X + (size_t)lane * NB + cellbase);

    for (int tc = 0; tc < TT; tc += CHUNK) {
        // stage prefetched chunk to LDS (transposed/padded), prefetch next
        xchunk[0][lane] = gq.x;
        xchunk[1][lane] = gq.y;
        xchunk[2][lane] = gq.z;
        xchunk[3][lane] = gq.w;
        if (tc + CHUNK < TT)
            gq = *(const float4*)(X + (size_t)(tc + CHUNK + lane) * NB + cellbase);

        for (int t4 = 0; t4 < CHUNK; t4 += 4) {
            // 4 steps' worth of x for my row: one broadcast ds_read_b128,
            // consumed only at each step's x-projection (last) -> latency buried
            const float4 xq = *(const float4*)&xchunk[row][t4];
            const float xs[4] = {xq.x, xq.y, xq.z, xq.w};

            #pragma unroll
            for (int u = 0; u < 4; ++u) {
                // gather h_{t-1} + gate accumulation: local + 15 DPP rors
                v2f gifA = bif, goA = bgo;
                v2f gifB; gifB.x = 0.0f; gifB.y = 0.0f;
                v2f goB;  goB.x  = 0.0f; goB.y  = 0.0f;
                {   // local contribution (r = 0)
                    v2f hk; hk.x = hn; hk.y = hn;
                    gifA = pkfma(wifU[0], hk, gifA);
                    goA  = pkfma(wgoU[0], hk, goA);
                }
#define XR(r) { \
                const int hr_##r = __builtin_amdgcn_update_dpp(0, hbits, ROR(r), 0xF, 0xF, true); \
                const float hf = __int_as_float(hr_##r); \
                v2f hk; hk.x = hf; hk.y = hf; \
                if ((r) < 8) { gifA = pkfma(wifU[r], hk, gifA); goA = pkfma(wgoU[r], hk, goA); } \
                else         { gifB = pkfma(wifU[r], hk, gifB); goB = pkfma(wgoU[r], hk, goB); } }
                XR(1)  XR(2)  XR(3)  XR(4)  XR(5)
                XR(6)  XR(7)  XR(8)  XR(9)  XR(10)
                XR(11) XR(12) XR(13) XR(14) XR(15)
#undef XR
                v2f gif = gifA + gifB;     // v_pk_add_f32
                v2f ggo = goA + goB;
                v2f xvv; xvv.x = xs[u]; xvv.y = xs[u];
                gif = pkfma(xvv, wxif, gif);   // x-projection last
                ggo = pkfma(xvv, wxgo, ggo);

                // activations (pre-scaled: rcp(1+exp2(g)) directly)
                const float si = __builtin_amdgcn_rcpf(1.0f + __builtin_amdgcn_exp2f(gif.x));
                const float sf = __builtin_amdgcn_rcpf(1.0f + __builtin_amdgcn_exp2f(gif.y));
                const float rg = __builtin_amdgcn_rcpf(1.0f + __builtin_amdgcn_exp2f(ggo.x));
                const float so = __builtin_amdgcn_rcpf(1.0f + __builtin_amdgcn_exp2f(ggo.y));
                const float tg = fmaf(-2.0f, rg, 1.0f);
                cst = fmaf(sf, cst, si * tg);
                const float rc   = __builtin_amdgcn_rcpf(1.0f + __builtin_amdgcn_exp2f(SPOS * cst));
                const float m2so = -2.0f * so;
                hn    = fmaf(m2so, rc, so);
                hbits = __float_as_int(hn);

                // fc output for step t: ring all-reduce of hn*fcw over the row
                // (independent of next step's ror/gate chain -> overlaps it)
                float p = hn * fcwj;
                p += __int_as_float(__builtin_amdgcn_update_dpp(0, __float_as_int(p), ROR(8), 0xF, 0xF, true));
                p += __int_as_float(__builtin_amdgcn_update_dpp(0, __float_as_int(p), ROR(4), 0xF, 0xF, true));
                p += __int_as_float(__builtin_amdgcn_update_dpp(0, __float_as_int(p), ROR(2), 0xF, 0xF, true));
                p += __int_as_float(__builtin_amdgcn_update_dpp(0, __float_as_int(p), ROR(1), 0xF, 0xF, true));
                if (j == 0) out[(size_t)(tc + t4 + u) * NB + cell] = p + fcb;
            }
        }
    }
}

extern "C" void kernel_launch(void* const* d_in, const int* in_sizes, int n_in,
                              void* d_out, int out_size, void* d_ws, size_t ws_size,
                              hipStream_t stream) {
    const float* X    = (const float*)d_in[0];
    const float* W_ih = (const float*)d_in[1];
    const float* W_hh = (const float*)d_in[2];
    const float* b_ih = (const float*)d_in[3];
    const float* b_hh = (const float*)d_in[4];
    const float* fc_w = (const float*)d_in[5];
    const float* fc_b = (const float*)d_in[6];
    float* out = (float*)d_out;

    const int grid = NB / RPW;   // 1024 single-wave blocks: every SIMD busy
    lstm_fused<<<grid, 64, 0, stream>>>(X, W_ih, W_hh, b_ih, b_hh, fc_w, fc_b, out);
}